// Round 3
// baseline (321.030 us; speedup 1.0000x reference)
//
#include <hip/hip_runtime.h>
#include <hip/hip_bf16.h>
#include <stdint.h>

typedef __bf16 bf16;
typedef __bf16 bf16x8 __attribute__((ext_vector_type(8)));
typedef float floatx4 __attribute__((ext_vector_type(4)));

#define D_MODEL 1024
#define SEQ 2048
#define NHEADS 16
#define DH 64
#define BATCH 2
#define MROWS (BATCH * SEQ)  // 4096

// ---------------------------------------------------------------------------
// NT GEMM: C[m,n] = sum_k A[m,k] * W[n,k].  A: f32 or bf16; W: f32; C: f32 or
// bf16.  Internally converts to bf16 and uses 16x16x32 bf16 MFMA (no fp32
// MFMA on CDNA4).  128x128 tile, BK=32, 4 waves, 4x4 MFMAs/wave.
// ---------------------------------------------------------------------------
template <typename AT, typename CT>
__global__ __launch_bounds__(256) void gemm_nt(
    const AT* __restrict__ A,
    const float* W0, const float* W1, const float* W2,
    CT* C0, CT* C1, CT* C2,
    int M, int N, int K) {
  const int z = blockIdx.z;
  const float* W = (z == 0) ? W0 : (z == 1) ? W1 : W2;
  CT* C = (z == 0) ? C0 : (z == 1) ? C1 : C2;

  __shared__ bf16 As[128 * 32];  // row-major [128][32]
  __shared__ bf16 Bs[128 * 32];

  const int tid = threadIdx.x;
  const int lane = tid & 63;
  const int w = tid >> 6;
  const int lo16 = lane & 15;
  const int quad = lane >> 4;
  const int wy = w >> 1, wx = w & 1;

  const int m0 = blockIdx.y * 128;
  const int n0 = blockIdx.x * 128;

  // staging: 4 threads per 32-elem row; each thread does rows r0 and r0+64,
  // 8 elements starting at c0.
  const int r0 = tid >> 2;
  const int c0 = (tid & 3) * 8;

  const floatx4 fz = {0.f, 0.f, 0.f, 0.f};
  floatx4 acc[4][4];
#pragma unroll
  for (int i = 0; i < 4; i++)
#pragma unroll
    for (int j = 0; j < 4; j++) acc[i][j] = fz;

  for (int k0 = 0; k0 < K; k0 += 32) {
    // ---- global -> registers (convert to bf16) ----
    bf16x8 a[2], b[2];
#pragma unroll
    for (int h = 0; h < 2; h++) {
      const size_t arow = (size_t)(m0 + h * 64 + r0) * K + k0 + c0;
      if constexpr (sizeof(AT) == 4) {
        floatx4 f0 = *(const floatx4*)&A[arow];
        floatx4 f1 = *(const floatx4*)&A[arow + 4];
#pragma unroll
        for (int j = 0; j < 4; j++) { a[h][j] = (bf16)f0[j]; a[h][4 + j] = (bf16)f1[j]; }
      } else {
        a[h] = *(const bf16x8*)&A[arow];
      }
      const size_t brow = (size_t)(n0 + h * 64 + r0) * K + k0 + c0;
      floatx4 g0 = *(const floatx4*)&W[brow];
      floatx4 g1 = *(const floatx4*)&W[brow + 4];
#pragma unroll
      for (int j = 0; j < 4; j++) { b[h][j] = (bf16)g0[j]; b[h][4 + j] = (bf16)g1[j]; }
    }

    __syncthreads();  // prior iteration's LDS reads complete
#pragma unroll
    for (int h = 0; h < 2; h++) {
      *(bf16x8*)&As[(h * 64 + r0) * 32 + c0] = a[h];
      *(bf16x8*)&Bs[(h * 64 + r0) * 32 + c0] = b[h];
    }
    __syncthreads();  // staging visible

    bf16x8 af[4], bfr[4];
#pragma unroll
    for (int t = 0; t < 4; t++) {
      af[t]  = *(const bf16x8*)&As[(wy * 64 + t * 16 + lo16) * 32 + quad * 8];
      bfr[t] = *(const bf16x8*)&Bs[(wx * 64 + t * 16 + lo16) * 32 + quad * 8];
    }
#pragma unroll
    for (int mt = 0; mt < 4; mt++)
#pragma unroll
      for (int nt = 0; nt < 4; nt++)
        acc[mt][nt] = __builtin_amdgcn_mfma_f32_16x16x32_bf16(af[mt], bfr[nt], acc[mt][nt], 0, 0, 0);
  }

  // C/D layout: col=lane&15, row=quad*4+reg (measured m89/m91)
#pragma unroll
  for (int mt = 0; mt < 4; mt++) {
#pragma unroll
    for (int nt = 0; nt < 4; nt++) {
#pragma unroll
      for (int r = 0; r < 4; r++) {
        const int row = m0 + wy * 64 + mt * 16 + quad * 4 + r;
        const int col = n0 + wx * 64 + nt * 16 + lo16;
        C[(size_t)row * N + col] = (CT)acc[mt][nt][r];
      }
    }
  }
}

// ---------------------------------------------------------------------------
// Causal flash attention. Q,K,V bf16 in [B, S, H*DH] row-major.
// Block = 256 thr (4 waves), 64 q-rows per block (16/wave), KV tiles of 64.
// ---------------------------------------------------------------------------
__global__ __launch_bounds__(256) void attn_causal(
    const bf16* __restrict__ Q, const bf16* __restrict__ Kg,
    const bf16* __restrict__ Vg, bf16* __restrict__ O) {
  __shared__ bf16 Ks[64 * 64];     // [kv][d]
  __shared__ bf16 Vs[64 * 64];     // [kv][d]
  __shared__ bf16 Ps[4][16 * 64];  // per-wave P: C-layout -> A-layout bridge

  const int tid = threadIdx.x;
  const int lane = tid & 63;
  const int w = tid >> 6;
  const int lo16 = lane & 15;
  const int quad = lane >> 4;

  const int q0 = blockIdx.x * 64;
  const int h = blockIdx.y;
  const int b = blockIdx.z;
  const size_t base = (size_t)b * SEQ * D_MODEL + (size_t)h * DH;

  // Q fragments: A-layout A[m=lane&15][k=quad*8+j] (m120)
  const int qrow = q0 + w * 16 + lo16;
  bf16x8 qf[2];
#pragma unroll
  for (int ks = 0; ks < 2; ks++)
    qf[ks] = *(const bf16x8*)&Q[base + (size_t)qrow * D_MODEL + ks * 32 + quad * 8];

  const floatx4 fz = {0.f, 0.f, 0.f, 0.f};
  floatx4 oacc[4];
#pragma unroll
  for (int dt = 0; dt < 4; dt++) oacc[dt] = fz;
  float m_i[4], l_i[4];
#pragma unroll
  for (int r = 0; r < 4; r++) { m_i[r] = -1.0e9f; l_i[r] = 0.f; }

  const int kr = tid >> 3;  // 0..31 (8 threads per 64-elem row)
  const int kc = (tid & 7) * 8;

  const int ntiles = q0 / 64 + 1;  // causal
  for (int t = 0; t < ntiles; t++) {
    const int j0 = t * 64;
    bf16x8 kv[2], vv[2];
#pragma unroll
    for (int c = 0; c < 2; c++) {
      kv[c] = *(const bf16x8*)&Kg[base + (size_t)(j0 + c * 32 + kr) * D_MODEL + kc];
      vv[c] = *(const bf16x8*)&Vg[base + (size_t)(j0 + c * 32 + kr) * D_MODEL + kc];
    }
    __syncthreads();
#pragma unroll
    for (int c = 0; c < 2; c++) {
      *(bf16x8*)&Ks[(c * 32 + kr) * 64 + kc] = kv[c];
      *(bf16x8*)&Vs[(c * 32 + kr) * 64 + kc] = vv[c];
    }
    __syncthreads();

    // S = Q K^T (per-wave 16x64)
    floatx4 sacc[4];
#pragma unroll
    for (int nt = 0; nt < 4; nt++) sacc[nt] = fz;
#pragma unroll
    for (int nt = 0; nt < 4; nt++) {
#pragma unroll
      for (int ks = 0; ks < 2; ks++) {
        bf16x8 kf = *(const bf16x8*)&Ks[(nt * 16 + lo16) * 64 + ks * 32 + quad * 8];
        sacc[nt] = __builtin_amdgcn_mfma_f32_16x16x32_bf16(qf[ks], kf, sacc[nt], 0, 0, 0);
      }
    }

    // scale 1/sqrt(64) + causal mask (finite -1e8, as in ref)
    float s[4][4];
    const int myrow = q0 + w * 16 + quad * 4;
#pragma unroll
    for (int nt = 0; nt < 4; nt++) {
      const int c = j0 + nt * 16 + lo16;
#pragma unroll
      for (int r = 0; r < 4; r++) {
        const float v = sacc[nt][r] * 0.125f;
        s[nt][r] = (c > myrow + r) ? -1.0e8f : v;
      }
    }

    // online softmax (row = 16 lanes of the quad-group x 4 nt)
    float p[4][4], alpha[4];
#pragma unroll
    for (int r = 0; r < 4; r++) {
      float mx = s[0][r];
#pragma unroll
      for (int nt = 1; nt < 4; nt++) mx = fmaxf(mx, s[nt][r]);
#pragma unroll
      for (int o = 1; o < 16; o <<= 1) mx = fmaxf(mx, __shfl_xor(mx, o));
      const float mn = fmaxf(m_i[r], mx);
      alpha[r] = __expf(m_i[r] - mn);
      m_i[r] = mn;
      float rs = 0.f;
#pragma unroll
      for (int nt = 0; nt < 4; nt++) { p[nt][r] = __expf(s[nt][r] - mn); rs += p[nt][r]; }
#pragma unroll
      for (int o = 1; o < 16; o <<= 1) rs += __shfl_xor(rs, o);
      l_i[r] = l_i[r] * alpha[r] + rs;
    }
#pragma unroll
    for (int dt = 0; dt < 4; dt++)
#pragma unroll
      for (int r = 0; r < 4; r++) oacc[dt][r] *= alpha[r];

    // P: C-layout regs -> LDS -> A-layout frags (m120 pattern)
#pragma unroll
    for (int nt = 0; nt < 4; nt++)
#pragma unroll
      for (int r = 0; r < 4; r++)
        Ps[w][(quad * 4 + r) * 64 + nt * 16 + lo16] = (bf16)p[nt][r];
    __syncthreads();

    // O += P V
#pragma unroll
    for (int ks = 0; ks < 2; ks++) {
      bf16x8 pf = *(const bf16x8*)&Ps[w][lo16 * 64 + ks * 32 + quad * 8];
#pragma unroll
      for (int dt = 0; dt < 4; dt++) {
        bf16x8 vf;
#pragma unroll
        for (int j = 0; j < 8; j++)
          vf[j] = Vs[(ks * 32 + quad * 8 + j) * 64 + dt * 16 + lo16];
        oacc[dt] = __builtin_amdgcn_mfma_f32_16x16x32_bf16(pf, vf, oacc[dt], 0, 0, 0);
      }
    }
  }

  // epilogue
#pragma unroll
  for (int dt = 0; dt < 4; dt++) {
#pragma unroll
    for (int r = 0; r < 4; r++) {
      const int row = q0 + w * 16 + quad * 4 + r;
      const float inv = 1.0f / fmaxf(l_i[r], 1.0e-20f);
      O[base + (size_t)row * D_MODEL + dt * 16 + lo16] = (bf16)(oacc[dt][r] * inv);
    }
  }
}

extern "C" void kernel_launch(void* const* d_in, const int* in_sizes, int n_in,
                              void* d_out, int out_size, void* d_ws, size_t ws_size,
                              hipStream_t stream) {
  const float* X  = (const float*)d_in[0];   // f32 per reference setup_inputs
  const float* Wq = (const float*)d_in[1];
  const float* Wk = (const float*)d_in[2];
  const float* Wv = (const float*)d_in[3];
  const float* Wo = (const float*)d_in[4];
  float* out = (float*)d_out;                // f32 per reference output

  const size_t elems = (size_t)MROWS * D_MODEL;
  bf16* Qb = (bf16*)d_ws;  // bf16 workspace: 8 MB each, 32 MB total
  bf16* Kb = Qb + elems;
  bf16* Vb = Kb + elems;
  bf16* Ob = Vb + elems;

  dim3 blk(256);
  gemm_nt<float, bf16><<<dim3(D_MODEL / 128, MROWS / 128, 3), blk, 0, stream>>>(
      X, Wq, Wk, Wv, Qb, Kb, Vb, MROWS, D_MODEL, D_MODEL);
  attn_causal<<<dim3(SEQ / 64, NHEADS, BATCH), blk, 0, stream>>>(Qb, Kb, Vb, Ob);
  gemm_nt<bf16, float><<<dim3(D_MODEL / 128, MROWS / 128, 1), blk, 0, stream>>>(
      Ob, Wo, Wo, Wo, out, out, out, MROWS, D_MODEL, D_MODEL);
}